// Round 2
// baseline (281.517 us; speedup 1.0000x reference)
//
#include <hip/hip_runtime.h>
#include <math.h>

// Problem constants
#define H    2048
#define NB   8192
#define KCH  64          // chunks along H
#define LCH  32          // steps per chunk (H / KCH)
#define BPC  8           // blocks per chunk: NB / (256 threads * 4 rollouts)

// Model constants: DT=0.05, WHEELBASE=2.5, MAX_STEER=0.5, MAX_ACC=5.0
#define DT_F 0.05f

// ---------------------------------------------------------------------------
// Kernel A: per-step constant scans (single block, 256 threads x 8 elems).
//   dv_j = DT*MAX_ACC*clip(a_j, -1, 1)
//   w_j  = (DT/WHEELBASE)*tan(clip(s_j, -0.5, 0.5))
//   C_i  = exclusive prefix of dv   (speed_i = s0 + C_i)
//   A_i  = exclusive prefix of w    (yaw_i = yaw0 + s0*A_i + B_i)
//   B_i  = exclusive prefix of C_j*w_j
// ---------------------------------------------------------------------------
__global__ __launch_bounds__(256) void precomp_scan(
    const float* __restrict__ accel, const float* __restrict__ steering,
    float* __restrict__ Cv, float* __restrict__ Av, float* __restrict__ Bv) {
  __shared__ double lds[256];
  const int t = threadIdx.x;

  double dv[8], w[8], Cl[8];
  for (int m = 0; m < 8; ++m) {
    int j = t * 8 + m;
    if (j < H - 1) {
      float a = accel[j];    a = fminf(1.0f, fmaxf(-1.0f, a));
      float s = steering[j]; s = fminf(0.5f, fmaxf(-0.5f, s));
      dv[m] = 0.25 * (double)a;          // DT * MAX_ACC
      w[m]  = 0.02 * tan((double)s);     // DT / WHEELBASE
    } else {
      dv[m] = 0.0; w[m] = 0.0;
    }
  }

  // scan 1: dv -> C (exclusive)
  {
    double tot = 0.0;
    for (int m = 0; m < 8; ++m) tot += dv[m];
    double run = tot; lds[t] = run; __syncthreads();
    for (int off = 1; off < 256; off <<= 1) {
      double y = (t >= off) ? lds[t - off] : 0.0;
      __syncthreads();
      run += y; lds[t] = run; __syncthreads();
    }
    double e = run - tot;
    for (int m = 0; m < 8; ++m) { Cl[m] = e; Cv[t * 8 + m] = (float)e; e += dv[m]; }
  }
  __syncthreads();

  // scan 2: w -> A (exclusive)
  {
    double tot = 0.0;
    for (int m = 0; m < 8; ++m) tot += w[m];
    double run = tot; lds[t] = run; __syncthreads();
    for (int off = 1; off < 256; off <<= 1) {
      double y = (t >= off) ? lds[t - off] : 0.0;
      __syncthreads();
      run += y; lds[t] = run; __syncthreads();
    }
    double e = run - tot;
    for (int m = 0; m < 8; ++m) { Av[t * 8 + m] = (float)e; e += w[m]; }
  }
  __syncthreads();

  // scan 3: C*w -> B (exclusive)
  {
    double v[8];
    for (int m = 0; m < 8; ++m) v[m] = Cl[m] * w[m];
    double tot = 0.0;
    for (int m = 0; m < 8; ++m) tot += v[m];
    double run = tot; lds[t] = run; __syncthreads();
    for (int off = 1; off < 256; off <<= 1) {
      double y = (t >= off) ? lds[t - off] : 0.0;
      __syncthreads();
      run += y; lds[t] = run; __syncthreads();
    }
    double e = run - tot;
    for (int m = 0; m < 8; ++m) { Bv[t * 8 + m] = (float)e; e += v[m]; }
  }
}

// ---------------------------------------------------------------------------
// Kernel B: closed-form yaw/speed outputs (float4 stores, 16 B/lane) +
// per-chunk partial sums of speed*cos(yaw), speed*sin(yaw).
// Grid: KCH * BPC blocks of 256; thread -> 4 consecutive rollouts.
// ---------------------------------------------------------------------------
__global__ __launch_bounds__(256) void yaw_speed_partials(
    const float4* __restrict__ syaw4, const float4* __restrict__ sspd4,
    const float* __restrict__ Cv, const float* __restrict__ Av,
    const float* __restrict__ Bv,
    float4* __restrict__ out4, float4* __restrict__ px4, float4* __restrict__ py4) {
  __shared__ float sC[LCH], sA[LCH], sB[LCH];
  const int k  = blockIdx.x >> 3;                       // / BPC
  const int t4 = ((blockIdx.x & (BPC - 1)) << 8) + threadIdx.x;  // rollout-group idx
  const int j0 = k * LCH;
  if (threadIdx.x < LCH) {
    sC[threadIdx.x] = Cv[j0 + threadIdx.x];
    sA[threadIdx.x] = Av[j0 + threadIdx.x];
    sB[threadIdx.x] = Bv[j0 + threadIdx.x];
  }
  __syncthreads();

  const float4 yaw0 = syaw4[t4];
  const float4 s0   = sspd4[t4];
  float4 accx = {0.f, 0.f, 0.f, 0.f}, accy = {0.f, 0.f, 0.f, 0.f};
  float4* __restrict__ oy4 = out4 + 2 * ((size_t)H * NB / 4);
  float4* __restrict__ os4 = out4 + 3 * ((size_t)H * NB / 4);

  for (int m = 0; m < LCH; ++m) {
    const float c = sC[m], a = sA[m], bb = sB[m];
    float4 spd, yw, sn, cs;
    spd.x = s0.x + c; spd.y = s0.y + c; spd.z = s0.z + c; spd.w = s0.w + c;
    yw.x = fmaf(s0.x, a, yaw0.x) + bb;
    yw.y = fmaf(s0.y, a, yaw0.y) + bb;
    yw.z = fmaf(s0.z, a, yaw0.z) + bb;
    yw.w = fmaf(s0.w, a, yaw0.w) + bb;
    __sincosf(yw.x, &sn.x, &cs.x);
    __sincosf(yw.y, &sn.y, &cs.y);
    __sincosf(yw.z, &sn.z, &cs.z);
    __sincosf(yw.w, &sn.w, &cs.w);
    const size_t idx4 = (size_t)(j0 + m) * (NB / 4) + t4;
    oy4[idx4] = yw;
    os4[idx4] = spd;
    accx.x = fmaf(spd.x, cs.x, accx.x); accx.y = fmaf(spd.y, cs.y, accx.y);
    accx.z = fmaf(spd.z, cs.z, accx.z); accx.w = fmaf(spd.w, cs.w, accx.w);
    accy.x = fmaf(spd.x, sn.x, accy.x); accy.y = fmaf(spd.y, sn.y, accy.y);
    accy.z = fmaf(spd.z, sn.z, accy.z); accy.w = fmaf(spd.w, sn.w, accy.w);
  }
  px4[k * (NB / 4) + t4] = accx;
  py4[k * (NB / 4) + t4] = accy;
}

// ---------------------------------------------------------------------------
// Kernel D: x/y outputs (float4). Chunk prefix offset is computed in-kernel
// by summing earlier chunks' partials (px/py = 4 MB -> LLC-resident reads),
// eliminating the separate scan kernel + round-trip.
// ---------------------------------------------------------------------------
__global__ __launch_bounds__(256) void xy_write(
    const float4* __restrict__ sx4, const float4* __restrict__ sy4,
    const float4* __restrict__ syaw4, const float4* __restrict__ sspd4,
    const float* __restrict__ Cv, const float* __restrict__ Av,
    const float* __restrict__ Bv,
    const float4* __restrict__ px4, const float4* __restrict__ py4,
    float4* __restrict__ out4) {
  __shared__ float sC[LCH], sA[LCH], sB[LCH];
  const int k  = blockIdx.x >> 3;
  const int t4 = ((blockIdx.x & (BPC - 1)) << 8) + threadIdx.x;
  const int j0 = k * LCH;
  if (threadIdx.x < LCH) {
    sC[threadIdx.x] = Cv[j0 + threadIdx.x];
    sA[threadIdx.x] = Av[j0 + threadIdx.x];
    sB[threadIdx.x] = Bv[j0 + threadIdx.x];
  }
  __syncthreads();

  // Lookback: exclusive prefix over earlier chunks' partial sums.
  float4 rx = {0.f, 0.f, 0.f, 0.f}, ry = {0.f, 0.f, 0.f, 0.f};
  for (int kk = 0; kk < k; ++kk) {
    const float4 tx = px4[kk * (NB / 4) + t4];
    const float4 ty = py4[kk * (NB / 4) + t4];
    rx.x += tx.x; rx.y += tx.y; rx.z += tx.z; rx.w += tx.w;
    ry.x += ty.x; ry.y += ty.y; ry.z += ty.z; ry.w += ty.w;
  }

  const float4 x0   = sx4[t4];
  const float4 y0   = sy4[t4];
  const float4 yaw0 = syaw4[t4];
  const float4 s0   = sspd4[t4];
  float4* __restrict__ outx4 = out4;
  float4* __restrict__ outy4 = out4 + ((size_t)H * NB / 4);

  for (int m = 0; m < LCH; ++m) {
    const float c = sC[m], a = sA[m], bb = sB[m];
    float4 spd, yw, sn, cs, wx, wy;
    spd.x = s0.x + c; spd.y = s0.y + c; spd.z = s0.z + c; spd.w = s0.w + c;
    yw.x = fmaf(s0.x, a, yaw0.x) + bb;
    yw.y = fmaf(s0.y, a, yaw0.y) + bb;
    yw.z = fmaf(s0.z, a, yaw0.z) + bb;
    yw.w = fmaf(s0.w, a, yaw0.w) + bb;
    __sincosf(yw.x, &sn.x, &cs.x);
    __sincosf(yw.y, &sn.y, &cs.y);
    __sincosf(yw.z, &sn.z, &cs.z);
    __sincosf(yw.w, &sn.w, &cs.w);
    wx.x = fmaf(DT_F, rx.x, x0.x); wx.y = fmaf(DT_F, rx.y, x0.y);
    wx.z = fmaf(DT_F, rx.z, x0.z); wx.w = fmaf(DT_F, rx.w, x0.w);
    wy.x = fmaf(DT_F, ry.x, y0.x); wy.y = fmaf(DT_F, ry.y, y0.y);
    wy.z = fmaf(DT_F, ry.z, y0.z); wy.w = fmaf(DT_F, ry.w, y0.w);
    const size_t idx4 = (size_t)(j0 + m) * (NB / 4) + t4;
    outx4[idx4] = wx;
    outy4[idx4] = wy;
    rx.x = fmaf(spd.x, cs.x, rx.x); rx.y = fmaf(spd.y, cs.y, rx.y);
    rx.z = fmaf(spd.z, cs.z, rx.z); rx.w = fmaf(spd.w, cs.w, rx.w);
    ry.x = fmaf(spd.x, sn.x, ry.x); ry.y = fmaf(spd.y, sn.y, ry.y);
    ry.z = fmaf(spd.z, sn.z, ry.z); ry.w = fmaf(spd.w, sn.w, ry.w);
  }
}

// ---------------------------------------------------------------------------
extern "C" void kernel_launch(void* const* d_in, const int* in_sizes, int n_in,
                              void* d_out, int out_size, void* d_ws, size_t ws_size,
                              hipStream_t stream) {
  const float* start_x     = (const float*)d_in[0];
  const float* start_y     = (const float*)d_in[1];
  const float* start_yaw   = (const float*)d_in[2];
  const float* start_speed = (const float*)d_in[3];
  const float* accel       = (const float*)d_in[4];
  const float* steering    = (const float*)d_in[5];

  // Workspace layout (floats): C[H], A[H], B[H], px[KCH*NB], py[KCH*NB]
  float* ws  = (float*)d_ws;
  float* Cv  = ws;
  float* Av  = ws + H;
  float* Bv  = ws + 2 * H;
  float* px  = ws + 3 * H;                       // 24 KB offset -> 16B aligned
  float* py  = px + (size_t)KCH * NB;

  precomp_scan<<<1, 256, 0, stream>>>(accel, steering, Cv, Av, Bv);
  yaw_speed_partials<<<KCH * BPC, 256, 0, stream>>>(
      (const float4*)start_yaw, (const float4*)start_speed,
      Cv, Av, Bv, (float4*)d_out, (float4*)px, (float4*)py);
  xy_write<<<KCH * BPC, 256, 0, stream>>>(
      (const float4*)start_x, (const float4*)start_y,
      (const float4*)start_yaw, (const float4*)start_speed,
      Cv, Av, Bv, (const float4*)px, (const float4*)py, (float4*)d_out);
}